// Round 14
// baseline (116.151 us; speedup 1.0000x reference)
//
#include <hip/hip_runtime.h>
#include <math.h>

#define DIM 2048          // INPUT_DIM
#define NF 2048           // N_FORMULAS
#define LPF 16            // LITERALS_PER_FORMULA
#define LTOT (NF * LPF)   // 32768
#define BETA 0.4f
#define EPS 1.0f
#define NDCH 64           // d-chunks for the reduction
#define DCH (DIM / NDCH)  // 32 rows per chunk

typedef float f32x4 __attribute__((ext_vector_type(4)));

// ---------------------------------------------------------------------------
// Kernel A: per-formula partial reduction + LLC prefetch of both inputs.
// grid (NF/256, NDCH) = 512 blocks. Scalar but fully-coalesced loads.
// ws layout: [NDCH][3][NF] floats, then ws2[NF].  (unchanged)
// ---------------------------------------------------------------------------
__global__ void reduce_prefetch(const float* __restrict__ lm,
                                const float* __restrict__ frm,
                                float* __restrict__ ws) {
    const int f = blockIdx.x * 256 + threadIdx.x;    // formula column
    const int d0 = blockIdx.y * DCH;

    float sq = 0.0f, l1 = 0.0f, cnt = 0.0f;
    #pragma unroll 8
    for (int i = 0; i < DCH; ++i) {
        const size_t off = ((size_t)(d0 + i) << 11) + f;   // row stride 2048
        float x = lm[off];
        float r = frm[off];
        sq  = fmaf(x * x, r, sq);
        l1  = fmaf(fabsf(x), r, l1);
        cnt += r;
    }

    float* w = ws + (size_t)blockIdx.y * 3 * NF;
    w[0 * NF + f] = sq;
    w[1 * NF + f] = l1;
    w[2 * NF + f] = cnt;
}

// ---------------------------------------------------------------------------
// Kernel B: expansion, nt stores. R14 change vs R13 (single variable):
// grid 512 -> 256 blocks = 1 block/CU (fillBuffer's concurrency shape),
// 16 consecutive rows (512 KB contiguous) per block. Same software
// pipeline: prefetch row d+1's 32 values during row d's 32-store nt burst.
// ---------------------------------------------------------------------------
__global__ void expand_stream(const float* __restrict__ lm,
                              const float* __restrict__ frm,
                              f32x4* __restrict__ out0,
                              f32x4* __restrict__ out1) {
    const int t = threadIdx.x;
    const int bx = blockIdx.x;                   // 0..255
    const bool is1 = bx >= 128;
    const int base = (is1 ? bx - 128 : bx) * 16; // first of 16 rows
    const float* src = is1 ? frm : lm;
    f32x4* outb = is1 ? out1 : out0;

    float cur[32], nxt[32];
    const float* row0 = src + ((size_t)base << 11) + (t >> 2);
    #pragma unroll
    for (int i = 0; i < 32; ++i)
        cur[i] = row0[i * 64];                   // 4-lane broadcast segments

    for (int rr = 0; rr < 16; ++rr) {
        const int d = base + rr;
        if (rr < 15) {                           // prefetch next row
            const float* rown = src + ((size_t)(d + 1) << 11) + (t >> 2);
            #pragma unroll
            for (int i = 0; i < 32; ++i)
                nxt[i] = rown[i * 64];
        }
        if (!is1) {
            #pragma unroll
            for (int i = 0; i < 32; ++i)
                cur[i] = (fabsf(cur[i]) > EPS) ? 1.0f : 0.0f;
        }
        f32x4* dst = outb + ((size_t)d << 13);   // row base, 8192 f4
        #pragma unroll
        for (int i = 0; i < 32; ++i) {
            f32x4 q = { cur[i], cur[i], cur[i], cur[i] };
            __builtin_nontemporal_store(q, &dst[i * 256 + t]);
        }
        #pragma unroll
        for (int i = 0; i < 32; ++i)
            cur[i] = nxt[i];
    }
}

// ---------------------------------------------------------------------------
// Kernel C: per-formula term from chunk partials. grid = NF/256 blocks.
// ---------------------------------------------------------------------------
__global__ void formula_term_kernel(const float* __restrict__ ws,
                                    const float* __restrict__ alpha,
                                    float* __restrict__ ws2) {
    const int f = blockIdx.x * blockDim.x + threadIdx.x;
    float sig = 1.0f / (1.0f + expf(-alpha[0]));
    float w_l2 = (1.0f - sig) * 0.5f;
    float w_l1 = sig;

    float sq = 0.0f, l1 = 0.0f, cnt = 0.0f;
    for (int c = 0; c < NDCH; ++c) {
        const float* w = ws + (size_t)c * 3 * NF;
        sq  += w[0 * NF + f];
        l1  += w[1 * NF + f];
        cnt += w[2 * NF + f];
    }
    float l2t = fabsf(sq / cnt - BETA * EPS * EPS);
    float l1t = fabsf(l1 / cnt - BETA * EPS);
    ws2[f] = l2t * w_l2 + l1t * w_l1;
}

// ---------------------------------------------------------------------------
// Kernel D: mean over formulas. 1 block, deterministic LDS tree.
// ---------------------------------------------------------------------------
__global__ void final_sum_kernel(const float* __restrict__ ws2,
                                 float* __restrict__ out_scalar) {
    __shared__ float red[256];
    const int t = threadIdx.x;
    float total = 0.0f;
    for (int k = 0; k < NF / 256; ++k)
        total += ws2[t + k * 256];
    red[t] = total;
    __syncthreads();
    for (int s = 128; s > 0; s >>= 1) {
        if (t < s) red[t] += red[t + s];
        __syncthreads();
    }
    if (t == 0) out_scalar[0] = red[0] / (float)NF;
}

extern "C" void kernel_launch(void* const* d_in, const int* in_sizes, int n_in,
                              void* d_out, int out_size, void* d_ws, size_t ws_size,
                              hipStream_t stream) {
    const float* lm    = (const float*)d_in[0];  // learnable_mask [D, F]
    const float* alpha = (const float*)d_in[1];  // elastic_net_alpha [1]
    const float* frm   = (const float*)d_in[2];  // formulas_random_mask [D, F]
    // d_in[3] = formula_id_per_literal (implicit: l // 16)

    float* out = (float*)d_out;
    float* ws  = (float*)d_ws;   // needs (NDCH*3*NF + NF)*4 = 1.58 MB

    const size_t big = (size_t)DIM * LTOT;       // 67,108,864 per output
    f32x4* out0 = (f32x4*)out;                   // learnable_binary_mask
    f32x4* out1 = (f32x4*)(out + big);           // literals_random_mask
    float* out_scalar = out + 2 * big;           // elastic_net_reg
    float* ws2 = ws + (size_t)NDCH * 3 * NF;

    // A: reduction partials + LLC prefetch of both inputs (reads phase)
    dim3 gridA(NF / 256, NDCH);
    reduce_prefetch<<<gridA, 256, 0, stream>>>(lm, frm, ws);

    // B: nt expansion, 1 block/CU (256 blocks, 16 rows each)
    expand_stream<<<256, 256, 0, stream>>>(lm, frm, out0, out1);

    // C/D: tiny epilogues
    formula_term_kernel<<<NF / 256, 256, 0, stream>>>(ws, alpha, ws2);
    final_sum_kernel<<<1, 256, 0, stream>>>(ws2, out_scalar);
}